// Round 1
// 83.977 us; speedup vs baseline: 1.0856x; 1.0856x over previous
//
#include <hip/hip_runtime.h>
#include <math.h>

#define BB 8
#define NN 2048
#define IND 128
#define OUTD 64
#define NEG 0.2f

typedef __attribute__((ext_vector_type(4))) float f32x4;
typedef __attribute__((ext_vector_type(2))) _Float16 h2;
typedef __attribute__((ext_vector_type(8))) _Float16 half8;

// f32 -> f16 bits (RNE via cast)
__device__ __forceinline__ unsigned short f2h(float f) {
    union { _Float16 h; unsigned short u; } c;
    c.h = (_Float16)f;
    return c.u;
}

// ---------------------------------------------------------------------------
// Kernel 1: hp = h @ W_fc + b_fc ; s = hp@a_src ; d -> F=exp(d), H=exp(NEG*d)
// 64 rows/block x 512 threads (grid 256 = 1 block/CU, 8 waves/CU = 2/SIMD for
// latency hiding; was 32x256 = 1 wave/SIMD). Per-thread work unchanged:
// 2 rows x 4 cols, all LDS reads b128.
// Emits hpT2 chunk-tiled **f16** [b][cj=j/8][o][j%8] for f16-MFMA B-frags
// (f16 11-bit mantissa > bf16 8-bit; range |hp| small -> safe).
// F,H stored f16 so kernel 2 can consume them with packed-f16 math.
// ---------------------------------------------------------------------------
__global__ __launch_bounds__(512) void gat_proj_kernel(
    const float* __restrict__ h, const float* __restrict__ W,
    const float* __restrict__ bfc, const float* __restrict__ asrc,
    const float* __restrict__ adst,
    unsigned short* __restrict__ hpT2, float* __restrict__ s,
    _Float16* __restrict__ F, _Float16* __restrict__ H)
{
    __shared__ float Wl[IND * OUTD];   // 32 KB  [k][o]
    __shared__ float hl[64 * 132];     // 33.8 KB [r][k], pad 132 (16B-aligned)

    const int t  = threadIdx.x;
    const int R0 = blockIdx.x * 64;

    const float4* W4 = (const float4*)W;
    float4*       Wl4 = (float4*)Wl;
    #pragma unroll
    for (int k2 = 0; k2 < 4; ++k2) Wl4[t + k2 * 512] = W4[t + k2 * 512];

    const float4* h4 = (const float4*)(h + (size_t)R0 * IND);
    #pragma unroll
    for (int k2 = 0; k2 < 4; ++k2) {
        const int idx = t + k2 * 512;      // float4 index
        const int row = idx >> 5, c4 = idx & 31;
        *(float4*)&hl[row * 132 + c4 * 4] = h4[idx];
    }
    __syncthreads();

    const int r0 = (t >> 4) * 2;           // 2 rows per thread (0..62)
    const int o0 = (t & 15) * 4;           // 4 cols per thread
    const float4 bias = *(const float4*)(bfc + o0);
    float4 a0 = bias, a1 = bias;

    #pragma unroll 2
    for (int kc = 0; kc < IND; kc += 4) {
        const float4 w0 = *(const float4*)&Wl[(kc + 0) * OUTD + o0];
        const float4 w1 = *(const float4*)&Wl[(kc + 1) * OUTD + o0];
        const float4 w2 = *(const float4*)&Wl[(kc + 2) * OUTD + o0];
        const float4 w3 = *(const float4*)&Wl[(kc + 3) * OUTD + o0];
        const float4 h0 = *(const float4*)&hl[(r0 + 0) * 132 + kc];
        const float4 h1 = *(const float4*)&hl[(r0 + 1) * 132 + kc];

        a0.x = fmaf(h0.x, w0.x, a0.x); a0.y = fmaf(h0.x, w0.y, a0.y);
        a0.z = fmaf(h0.x, w0.z, a0.z); a0.w = fmaf(h0.x, w0.w, a0.w);
        a0.x = fmaf(h0.y, w1.x, a0.x); a0.y = fmaf(h0.y, w1.y, a0.y);
        a0.z = fmaf(h0.y, w1.z, a0.z); a0.w = fmaf(h0.y, w1.w, a0.w);
        a0.x = fmaf(h0.z, w2.x, a0.x); a0.y = fmaf(h0.z, w2.y, a0.y);
        a0.z = fmaf(h0.z, w2.z, a0.z); a0.w = fmaf(h0.z, w2.w, a0.w);
        a0.x = fmaf(h0.w, w3.x, a0.x); a0.y = fmaf(h0.w, w3.y, a0.y);
        a0.z = fmaf(h0.w, w3.z, a0.z); a0.w = fmaf(h0.w, w3.w, a0.w);

        a1.x = fmaf(h1.x, w0.x, a1.x); a1.y = fmaf(h1.x, w0.y, a1.y);
        a1.z = fmaf(h1.x, w0.z, a1.z); a1.w = fmaf(h1.x, w0.w, a1.w);
        a1.x = fmaf(h1.y, w1.x, a1.x); a1.y = fmaf(h1.y, w1.y, a1.y);
        a1.z = fmaf(h1.y, w1.z, a1.z); a1.w = fmaf(h1.y, w1.w, a1.w);
        a1.x = fmaf(h1.z, w2.x, a1.x); a1.y = fmaf(h1.z, w2.y, a1.y);
        a1.z = fmaf(h1.z, w2.z, a1.z); a1.w = fmaf(h1.z, w2.w, a1.w);
        a1.x = fmaf(h1.w, w3.x, a1.x); a1.y = fmaf(h1.w, w3.y, a1.y);
        a1.z = fmaf(h1.w, w3.z, a1.z); a1.w = fmaf(h1.w, w3.w, a1.w);
    }

    // ---- write hpT2 chunk-tiled f16: [b][cj][o][8], 2 rows -> ushort2 ----
    const int b   = R0 >> 11;
    const int jb0 = (R0 & 2047) + r0;
    const int cj  = jb0 >> 3;
    const int sub = jb0 & 7;               // even
    unsigned short* cbase = hpT2 + (((size_t)(b * 256 + cj)) * OUTD) * 8;
    {
        ushort2 v;
        v.x = f2h(a0.x); v.y = f2h(a1.x);
        *(ushort2*)(cbase + (o0 + 0) * 8 + sub) = v;
        v.x = f2h(a0.y); v.y = f2h(a1.y);
        *(ushort2*)(cbase + (o0 + 1) * 8 + sub) = v;
        v.x = f2h(a0.z); v.y = f2h(a1.z);
        *(ushort2*)(cbase + (o0 + 2) * 8 + sub) = v;
        v.x = f2h(a0.w); v.y = f2h(a1.w);
        *(ushort2*)(cbase + (o0 + 3) * 8 + sub) = v;
    }

    // ---- s, F, H ----
    const float4 as4 = *(const float4*)(asrc + o0);
    const float4 ad4 = *(const float4*)(adst + o0);
    float vs[2], vd[2];
    vs[0] = a0.x*as4.x + a0.y*as4.y + a0.z*as4.z + a0.w*as4.w;
    vs[1] = a1.x*as4.x + a1.y*as4.y + a1.z*as4.z + a1.w*as4.w;
    vd[0] = a0.x*ad4.x + a0.y*ad4.y + a0.z*ad4.z + a0.w*ad4.w;
    vd[1] = a1.x*ad4.x + a1.y*ad4.y + a1.z*ad4.z + a1.w*ad4.w;
    #pragma unroll
    for (int msk = 1; msk <= 8; msk <<= 1) {
        vs[0] += __shfl_xor(vs[0], msk);
        vs[1] += __shfl_xor(vs[1], msk);
        vd[0] += __shfl_xor(vd[0], msk);
        vd[1] += __shfl_xor(vd[1], msk);
    }
    if ((t & 15) == 0) {
        #pragma unroll
        for (int r = 0; r < 2; ++r) {
            s[R0 + r0 + r] = vs[r];
            F[R0 + r0 + r] = (_Float16)__expf(vd[r]);
            H[R0 + r0 + r] = (_Float16)__expf(NEG * vd[r]);
        }
    }
}

// ---------------------------------------------------------------------------
// Kernel 2: softmax(leakyrelu(s_i+d_j+b)) @ hp via f16 MFMA.
// 512 threads (8 waves, j-split x8, 2 waves/SIMD — was 4 waves = 1/SIMD with
// every L2 latency exposed). Each wave: 64 rows (4 A-tiles) x 256-j range.
// Weights factorized exactly: exp(leaky(x)) = max(E_i*F_j, G_i*H_j), computed
// entirely in PACKED f16: v_pk_mul_f16 x2 + v_pk_max_f16 per 2 elems
// (1.5 VALU/elem vs 3.5 in the f32+cvt_pk_bf16 version), result IS the MFMA
// A-frag. Range: |scores|<~8 -> EF <= e^8 << 65504, no overflow; f16 11-bit
// mantissa > bf16 8-bit previously fed to MFMA.
// Denominator via ones-B MFMA (numerator-consistent f16 row sums).
// LDS combine two-stage (waves 4..7 write, 0..3 add) to stay at ~70 KB.
// ---------------------------------------------------------------------------
__global__ __launch_bounds__(512) void gat_attn_kernel(
    const unsigned short* __restrict__ hpT2, const float* __restrict__ s,
    const _Float16* __restrict__ F, const _Float16* __restrict__ H,
    const float* __restrict__ battn_p, float* __restrict__ out)
{
    __shared__ float accl[4][64 * 66];   // 67.6 KB: combined partials
    __shared__ float ll[8][64];          // per-wave denominator partials

    const int t    = threadIdx.x;
    const int lane = t & 63;
    const int wv   = t >> 6;             // 0..7
    const int blk  = blockIdx.x;         // 0..255
    const int b    = blk >> 5;           // 32 row-groups per batch
    const int i0   = (blk & 31) * 64;
    const int m    = lane & 15;
    const int kc   = lane >> 4;          // k-chunk quad (0..3)

    const float battn = battn_p[0];
    h2 E2[4], G2[4];
    #pragma unroll
    for (int T = 0; T < 4; ++T) {
        const float smv = s[b * NN + i0 + T * 16 + m] + battn;
        const float Ef = __expf(smv);
        const float Gf = __expf(NEG * smv);
        E2[T] = (h2){(_Float16)Ef, (_Float16)Ef};
        G2[T] = (h2){(_Float16)Gf, (_Float16)Gf};
    }
    const _Float16* Fb = F + b * NN;
    const _Float16* Hb = H + b * NN;
    const _Float16* hb = (const _Float16*)hpT2 + (size_t)b * 256 * OUTD * 8;

    half8 ones;
    #pragma unroll
    for (int q = 0; q < 8; ++q) ones[q] = (_Float16)1.0f;

    f32x4 acc[4][4];                     // [tile][ot]
    f32x4 dacc[4];                       // [tile] denominator
    #pragma unroll
    for (int T = 0; T < 4; ++T) {
        dacc[T] = (f32x4){0.f, 0.f, 0.f, 0.f};
        #pragma unroll
        for (int ot = 0; ot < 4; ++ot) acc[T][ot] = (f32x4){0.f, 0.f, 0.f, 0.f};
    }

    const int jbase = wv * (NN / 8);     // this wave's 256-wide j range

    #pragma unroll 2
    for (int it = 0; it < NN / 8 / 32; ++it) {
        const int j0 = jbase + it * 32;
        // --- B-frags first (longest latency): hp[j0+kc*8..+7][ot*16+m] ---
        const size_t cb = ((size_t)((j0 >> 3) + kc)) * OUTD * 8;
        const half8 bf0 = *(const half8*)(hb + cb + (0 * 16 + m) * 8);
        const half8 bf1 = *(const half8*)(hb + cb + (1 * 16 + m) * 8);
        const half8 bf2 = *(const half8*)(hb + cb + (2 * 16 + m) * 8);
        const half8 bf3 = *(const half8*)(hb + cb + (3 * 16 + m) * 8);

        union { float4 q; h2 p[4]; } Ff, Hf;
        Ff.q = *(const float4*)(Fb + j0 + kc * 8);   // 8 f16 F values
        Hf.q = *(const float4*)(Hb + j0 + kc * 8);   // 8 f16 H values

        #pragma unroll
        for (int T = 0; T < 4; ++T) {
            union { half8 v; h2 p[4]; } af;
            af.p[0] = __builtin_elementwise_max(E2[T] * Ff.p[0], G2[T] * Hf.p[0]);
            af.p[1] = __builtin_elementwise_max(E2[T] * Ff.p[1], G2[T] * Hf.p[1]);
            af.p[2] = __builtin_elementwise_max(E2[T] * Ff.p[2], G2[T] * Hf.p[2]);
            af.p[3] = __builtin_elementwise_max(E2[T] * Ff.p[3], G2[T] * Hf.p[3]);

            acc[T][0] = __builtin_amdgcn_mfma_f32_16x16x32_f16(af.v, bf0, acc[T][0], 0, 0, 0);
            acc[T][1] = __builtin_amdgcn_mfma_f32_16x16x32_f16(af.v, bf1, acc[T][1], 0, 0, 0);
            acc[T][2] = __builtin_amdgcn_mfma_f32_16x16x32_f16(af.v, bf2, acc[T][2], 0, 0, 0);
            acc[T][3] = __builtin_amdgcn_mfma_f32_16x16x32_f16(af.v, bf3, acc[T][3], 0, 0, 0);
            dacc[T]   = __builtin_amdgcn_mfma_f32_16x16x32_f16(af.v, ones, dacc[T], 0, 0, 0);
        }
    }

    // denominator partials: D column 0 lives in m==0 lanes; row = kc*4 + reg
    if (m == 0) {
        #pragma unroll
        for (int T = 0; T < 4; ++T)
            #pragma unroll
            for (int r = 0; r < 4; ++r) ll[wv][T * 16 + kc * 4 + r] = dacc[T][r];
    }

    // two-stage combine: waves 4..7 write buffers 0..3, waves 0..3 add.
    // stride-66 pad: kc row-offset -> +8 banks, 2-way max (free)
    if (wv >= 4) {
        #pragma unroll
        for (int T = 0; T < 4; ++T) {
            #pragma unroll
            for (int r = 0; r < 4; ++r) {
                const int row = T * 16 + kc * 4 + r;
                accl[wv - 4][row * 66 + 0 * 16 + m] = acc[T][0][r];
                accl[wv - 4][row * 66 + 1 * 16 + m] = acc[T][1][r];
                accl[wv - 4][row * 66 + 2 * 16 + m] = acc[T][2][r];
                accl[wv - 4][row * 66 + 3 * 16 + m] = acc[T][3][r];
            }
        }
    }
    __syncthreads();
    if (wv < 4) {
        #pragma unroll
        for (int T = 0; T < 4; ++T) {
            #pragma unroll
            for (int r = 0; r < 4; ++r) {
                const int row = T * 16 + kc * 4 + r;
                accl[wv][row * 66 + 0 * 16 + m] += acc[T][0][r];
                accl[wv][row * 66 + 1 * 16 + m] += acc[T][1][r];
                accl[wv][row * 66 + 2 * 16 + m] += acc[T][2][r];
                accl[wv][row * 66 + 3 * 16 + m] += acc[T][3][r];
            }
        }
    }
    __syncthreads();

    // epilogue: combine 4 buffers + 8 denom partials, divide, ELU, store
    const int col = t & 63;
    const int r0e = (t >> 6) * 8;
    float* ob = out + (((size_t)b * NN + i0) * OUTD);
    #pragma unroll 4
    for (int r = 0; r < 8; ++r) {
        const int row = r0e + r;
        const float lsum = ((ll[0][row] + ll[1][row]) + (ll[2][row] + ll[3][row])) +
                           ((ll[4][row] + ll[5][row]) + (ll[6][row] + ll[7][row]));
        float v = (accl[0][row * 66 + col] + accl[1][row * 66 + col]) +
                  (accl[2][row * 66 + col] + accl[3][row * 66 + col]);
        v /= lsum;
        v = (v > 0.f) ? v : expm1f(v);
        ob[(size_t)row * OUTD + col] = v;
    }
}

// ---------------------------------------------------------------------------
extern "C" void kernel_launch(void* const* d_in, const int* in_sizes, int n_in,
                              void* d_out, int out_size, void* d_ws, size_t ws_size,
                              hipStream_t stream)
{
    const float* h     = (const float*)d_in[0];
    const float* W     = (const float*)d_in[1];
    const float* bfc   = (const float*)d_in[2];
    const float* asrc  = (const float*)d_in[3];
    const float* adst  = (const float*)d_in[4];
    const float* battn = (const float*)d_in[5];
    float* out = (float*)d_out;

    unsigned short* hpT2 = (unsigned short*)d_ws;            // 2 MB f16 tiled
    float*     s = (float*)((char*)d_ws + (size_t)BB * NN * OUTD * 2);
    _Float16*  F = (_Float16*)(s + (size_t)BB * NN);
    _Float16*  H = F + (size_t)BB * NN;

    gat_proj_kernel<<<(BB * NN) / 64, 512, 0, stream>>>(h, W, bfc, asrc, adst,
                                                        hpT2, s, F, H);
    gat_attn_kernel<<<BB * (NN / 64), 512, 0, stream>>>(hpT2, s, F, H, battn, out);
}

// Round 2
// 81.399 us; speedup vs baseline: 1.1200x; 1.0317x over previous
//
#include <hip/hip_runtime.h>
#include <math.h>

#define BB 8
#define NN 2048
#define IND 128
#define OUTD 64
#define NEG 0.2f

typedef __attribute__((ext_vector_type(4))) float f32x4;
typedef __attribute__((ext_vector_type(2))) _Float16 h2;
typedef __attribute__((ext_vector_type(8))) _Float16 half8;

// f32 -> f16 bits (RNE via cast)
__device__ __forceinline__ unsigned short f2h(float f) {
    union { _Float16 h; unsigned short u; } c;
    c.h = (_Float16)f;
    return c.u;
}

// ---------------------------------------------------------------------------
// Kernel 1 (MFMA rewrite): hp = h@W + b ; s = hp@a_src ; F=exp(d), H=exp(NEG*d)
// Old version was LDS-throughput-bound: 192 ds_read_b128/wave -> ~18K LDS
// cycles/CU (~7.7us). Now:
//   - A-frags (h) load DIRECTLY from global: frag k-layout (lane>>4)*8+e is 8
//     consecutive f32 per lane -> no h staging at all.
//   - W staged once/block into LDS transposed [o][k] as f16 hi/lo pair
//     (pad 136: o-stride 272B = 4 banks -> 2-way = free; b128 frag reads).
//   - 3-MFMA split (hi*hi + hi*lo + lo*hi, f32 acc, bias in C-init) keeps proj
//     ~f32-exact so the error budget stays with the attn f16 path.
// 512 thr / 64 rows / block, grid 256. Wave w: row-tile rt=w>>1, o-half nh=w&1.
// Per wave: 4 ksteps x 2 ntiles x 3 = 24 MFMA; LDS b128 reads 16/wave (was 192).
// ---------------------------------------------------------------------------
__global__ __launch_bounds__(512) void gat_proj_kernel(
    const float* __restrict__ h, const float* __restrict__ W,
    const float* __restrict__ bfc, const float* __restrict__ asrc,
    const float* __restrict__ adst,
    unsigned short* __restrict__ hpT2, float* __restrict__ s,
    _Float16* __restrict__ F, _Float16* __restrict__ H)
{
    __shared__ _Float16 WtH[64 * 136];   // [o][k] hi, pad 136
    __shared__ _Float16 WtL[64 * 136];   // [o][k] lo
    __shared__ float sps[64][2];         // s partials per o-half
    __shared__ float spd[64][2];         // d partials per o-half

    const int t    = threadIdx.x;
    const int lane = t & 63;
    const int wv   = t >> 6;             // 0..7
    const int R0   = blockIdx.x * 64;

    // ---- stage W transposed, f16 hi/lo split (scalar writes are wave-wide:
    //      ~256 ds_write_u16 instrs/CU ~ 0.3us) ----
    const float4* W4 = (const float4*)W;
    #pragma unroll
    for (int i = 0; i < 4; ++i) {
        const int idx = t + i * 512;     // 2048 float4 total
        union { float4 q; float f[4]; } w;
        w.q = W4[idx];
        const int k  = idx >> 4;         // 16 float4 per k-row
        const int o0 = (idx & 15) * 4;
        #pragma unroll
        for (int c = 0; c < 4; ++c) {
            const float v = w.f[c];
            const _Float16 hi = (_Float16)v;
            const _Float16 lo = (_Float16)(v - (float)hi);
            WtH[(o0 + c) * 136 + k] = hi;
            WtL[(o0 + c) * 136 + k] = lo;
        }
    }

    const int rt = wv >> 1;              // row tile (16 rows)
    const int nh = wv & 1;               // o half (32 cols)
    const int m  = lane & 15;
    const int g  = lane >> 4;            // k-group

    const int o_0 = nh * 32 + m;         // ntile 0 col
    const int o_1 = nh * 32 + 16 + m;    // ntile 1 col

    // ---- A-frags direct from global: rows R0+rt*16+m, k = ks*32+g*8+e ----
    const float* hrow = h + (size_t)(R0 + rt * 16 + m) * IND + g * 8;
    half8 ahi[4], alo[4];
    #pragma unroll
    for (int ks = 0; ks < 4; ++ks) {
        union { float4 q; float f[4]; } p0, p1;
        p0.q = *(const float4*)(hrow + ks * 32);
        p1.q = *(const float4*)(hrow + ks * 32 + 4);
        #pragma unroll
        for (int e = 0; e < 4; ++e) {
            const _Float16 hi0 = (_Float16)p0.f[e];
            ahi[ks][e] = hi0;
            alo[ks][e] = (_Float16)(p0.f[e] - (float)hi0);
            const _Float16 hi1 = (_Float16)p1.f[e];
            ahi[ks][4 + e] = hi1;
            alo[ks][4 + e] = (_Float16)(p1.f[e] - (float)hi1);
        }
    }

    // ---- accumulators init with bias (C layout: col=lane&15, row=g*4+r) ----
    f32x4 acc0, acc1;
    {
        const float b0 = bfc[o_0], b1 = bfc[o_1];
        acc0 = (f32x4){b0, b0, b0, b0};
        acc1 = (f32x4){b1, b1, b1, b1};
    }

    __syncthreads();

    #pragma unroll
    for (int ks = 0; ks < 4; ++ks) {
        const int kb = ks * 32 + g * 8;
        const half8 bh0 = *(const half8*)&WtH[o_0 * 136 + kb];
        const half8 bl0 = *(const half8*)&WtL[o_0 * 136 + kb];
        const half8 bh1 = *(const half8*)&WtH[o_1 * 136 + kb];
        const half8 bl1 = *(const half8*)&WtL[o_1 * 136 + kb];

        acc0 = __builtin_amdgcn_mfma_f32_16x16x32_f16(ahi[ks], bh0, acc0, 0, 0, 0);
        acc0 = __builtin_amdgcn_mfma_f32_16x16x32_f16(ahi[ks], bl0, acc0, 0, 0, 0);
        acc0 = __builtin_amdgcn_mfma_f32_16x16x32_f16(alo[ks], bh0, acc0, 0, 0, 0);

        acc1 = __builtin_amdgcn_mfma_f32_16x16x32_f16(ahi[ks], bh1, acc1, 0, 0, 0);
        acc1 = __builtin_amdgcn_mfma_f32_16x16x32_f16(ahi[ks], bl1, acc1, 0, 0, 0);
        acc1 = __builtin_amdgcn_mfma_f32_16x16x32_f16(alo[ks], bh1, acc1, 0, 0, 0);
    }

    // ---- hpT2 chunk-tiled f16 [b][cj][o][8]: lane holds 4 CONSECUTIVE rows
    //      (g*4+r) -> one ushort4 per ntile ----
    const int b   = R0 >> 11;
    const int jb0 = (R0 & 2047) + rt * 16 + g * 4;
    const int cj  = jb0 >> 3;
    const int sub = jb0 & 7;             // 0 or 4
    unsigned short* cbase = hpT2 + (((size_t)(b * 256 + cj)) * OUTD) * 8;
    {
        ushort4 u;
        u.x = f2h(acc0[0]); u.y = f2h(acc0[1]);
        u.z = f2h(acc0[2]); u.w = f2h(acc0[3]);
        *(ushort4*)(cbase + o_0 * 8 + sub) = u;
        u.x = f2h(acc1[0]); u.y = f2h(acc1[1]);
        u.z = f2h(acc1[2]); u.w = f2h(acc1[3]);
        *(ushort4*)(cbase + o_1 * 8 + sub) = u;
    }

    // ---- s, d partials over this wave's 32 cols, reduce across 16 lanes ----
    const float a_s0 = asrc[o_0], a_s1 = asrc[o_1];
    const float a_d0 = adst[o_0], a_d1 = adst[o_1];
    float ps[4], pd[4];
    #pragma unroll
    for (int r = 0; r < 4; ++r) {
        ps[r] = acc0[r] * a_s0 + acc1[r] * a_s1;
        pd[r] = acc0[r] * a_d0 + acc1[r] * a_d1;
    }
    #pragma unroll
    for (int msk = 1; msk <= 8; msk <<= 1) {
        #pragma unroll
        for (int r = 0; r < 4; ++r) {
            ps[r] += __shfl_xor(ps[r], msk);
            pd[r] += __shfl_xor(pd[r], msk);
        }
    }
    if (m == 0) {
        #pragma unroll
        for (int r = 0; r < 4; ++r) {
            const int row = rt * 16 + g * 4 + r;
            sps[row][nh] = ps[r];
            spd[row][nh] = pd[r];
        }
    }
    __syncthreads();
    if (t < 64) {
        const float sv = sps[t][0] + sps[t][1];
        const float dv = spd[t][0] + spd[t][1];
        s[R0 + t] = sv;
        F[R0 + t] = (_Float16)__expf(dv);
        H[R0 + t] = (_Float16)__expf(NEG * dv);
    }
}

// ---------------------------------------------------------------------------
// Kernel 2: softmax(leakyrelu(s_i+d_j+b)) @ hp via f16 MFMA.  (unchanged)
// 512 threads (8 waves, j-split x8, 2 waves/SIMD). Each wave: 64 rows
// (4 A-tiles) x 256-j range. Weights exp(leaky(x)) = max(E_i*F_j, G_i*H_j)
// computed entirely in packed f16; result IS the MFMA A-frag.
// Denominator via ones-B MFMA. Two-stage LDS combine keeps LDS at ~70 KB.
// ---------------------------------------------------------------------------
__global__ __launch_bounds__(512) void gat_attn_kernel(
    const unsigned short* __restrict__ hpT2, const float* __restrict__ s,
    const _Float16* __restrict__ F, const _Float16* __restrict__ H,
    const float* __restrict__ battn_p, float* __restrict__ out)
{
    __shared__ float accl[4][64 * 66];   // 67.6 KB: combined partials
    __shared__ float ll[8][64];          // per-wave denominator partials

    const int t    = threadIdx.x;
    const int lane = t & 63;
    const int wv   = t >> 6;             // 0..7
    const int blk  = blockIdx.x;         // 0..255
    const int b    = blk >> 5;           // 32 row-groups per batch
    const int i0   = (blk & 31) * 64;
    const int m    = lane & 15;
    const int kc   = lane >> 4;          // k-chunk quad (0..3)

    const float battn = battn_p[0];
    h2 E2[4], G2[4];
    #pragma unroll
    for (int T = 0; T < 4; ++T) {
        const float smv = s[b * NN + i0 + T * 16 + m] + battn;
        const float Ef = __expf(smv);
        const float Gf = __expf(NEG * smv);
        E2[T] = (h2){(_Float16)Ef, (_Float16)Ef};
        G2[T] = (h2){(_Float16)Gf, (_Float16)Gf};
    }
    const _Float16* Fb = F + b * NN;
    const _Float16* Hb = H + b * NN;
    const _Float16* hb = (const _Float16*)hpT2 + (size_t)b * 256 * OUTD * 8;

    half8 ones;
    #pragma unroll
    for (int q = 0; q < 8; ++q) ones[q] = (_Float16)1.0f;

    f32x4 acc[4][4];                     // [tile][ot]
    f32x4 dacc[4];                       // [tile] denominator
    #pragma unroll
    for (int T = 0; T < 4; ++T) {
        dacc[T] = (f32x4){0.f, 0.f, 0.f, 0.f};
        #pragma unroll
        for (int ot = 0; ot < 4; ++ot) acc[T][ot] = (f32x4){0.f, 0.f, 0.f, 0.f};
    }

    const int jbase = wv * (NN / 8);     // this wave's 256-wide j range

    #pragma unroll 2
    for (int it = 0; it < NN / 8 / 32; ++it) {
        const int j0 = jbase + it * 32;
        // --- B-frags first (longest latency): hp[j0+kc*8..+7][ot*16+m] ---
        const size_t cb = ((size_t)((j0 >> 3) + kc)) * OUTD * 8;
        const half8 bf0 = *(const half8*)(hb + cb + (0 * 16 + m) * 8);
        const half8 bf1 = *(const half8*)(hb + cb + (1 * 16 + m) * 8);
        const half8 bf2 = *(const half8*)(hb + cb + (2 * 16 + m) * 8);
        const half8 bf3 = *(const half8*)(hb + cb + (3 * 16 + m) * 8);

        union { float4 q; h2 p[4]; } Ff, Hf;
        Ff.q = *(const float4*)(Fb + j0 + kc * 8);   // 8 f16 F values
        Hf.q = *(const float4*)(Hb + j0 + kc * 8);   // 8 f16 H values

        #pragma unroll
        for (int T = 0; T < 4; ++T) {
            union { half8 v; h2 p[4]; } af;
            af.p[0] = __builtin_elementwise_max(E2[T] * Ff.p[0], G2[T] * Hf.p[0]);
            af.p[1] = __builtin_elementwise_max(E2[T] * Ff.p[1], G2[T] * Hf.p[1]);
            af.p[2] = __builtin_elementwise_max(E2[T] * Ff.p[2], G2[T] * Hf.p[2]);
            af.p[3] = __builtin_elementwise_max(E2[T] * Ff.p[3], G2[T] * Hf.p[3]);

            acc[T][0] = __builtin_amdgcn_mfma_f32_16x16x32_f16(af.v, bf0, acc[T][0], 0, 0, 0);
            acc[T][1] = __builtin_amdgcn_mfma_f32_16x16x32_f16(af.v, bf1, acc[T][1], 0, 0, 0);
            acc[T][2] = __builtin_amdgcn_mfma_f32_16x16x32_f16(af.v, bf2, acc[T][2], 0, 0, 0);
            acc[T][3] = __builtin_amdgcn_mfma_f32_16x16x32_f16(af.v, bf3, acc[T][3], 0, 0, 0);
            dacc[T]   = __builtin_amdgcn_mfma_f32_16x16x32_f16(af.v, ones, dacc[T], 0, 0, 0);
        }
    }

    // denominator partials: D column 0 lives in m==0 lanes; row = kc*4 + reg
    if (m == 0) {
        #pragma unroll
        for (int T = 0; T < 4; ++T)
            #pragma unroll
            for (int r = 0; r < 4; ++r) ll[wv][T * 16 + kc * 4 + r] = dacc[T][r];
    }

    // two-stage combine: waves 4..7 write buffers 0..3, waves 0..3 add.
    // stride-66 pad: kc row-offset -> +8 banks, 2-way max (free)
    if (wv >= 4) {
        #pragma unroll
        for (int T = 0; T < 4; ++T) {
            #pragma unroll
            for (int r = 0; r < 4; ++r) {
                const int row = T * 16 + kc * 4 + r;
                accl[wv - 4][row * 66 + 0 * 16 + m] = acc[T][0][r];
                accl[wv - 4][row * 66 + 1 * 16 + m] = acc[T][1][r];
                accl[wv - 4][row * 66 + 2 * 16 + m] = acc[T][2][r];
                accl[wv - 4][row * 66 + 3 * 16 + m] = acc[T][3][r];
            }
        }
    }
    __syncthreads();
    if (wv < 4) {
        #pragma unroll
        for (int T = 0; T < 4; ++T) {
            #pragma unroll
            for (int r = 0; r < 4; ++r) {
                const int row = T * 16 + kc * 4 + r;
                accl[wv][row * 66 + 0 * 16 + m] += acc[T][0][r];
                accl[wv][row * 66 + 1 * 16 + m] += acc[T][1][r];
                accl[wv][row * 66 + 2 * 16 + m] += acc[T][2][r];
                accl[wv][row * 66 + 3 * 16 + m] += acc[T][3][r];
            }
        }
    }
    __syncthreads();

    // epilogue: combine 4 buffers + 8 denom partials, divide, ELU, store
    const int col = t & 63;
    const int r0e = (t >> 6) * 8;
    float* ob = out + (((size_t)b * NN + i0) * OUTD);
    #pragma unroll 4
    for (int r = 0; r < 8; ++r) {
        const int row = r0e + r;
        const float lsum = ((ll[0][row] + ll[1][row]) + (ll[2][row] + ll[3][row])) +
                           ((ll[4][row] + ll[5][row]) + (ll[6][row] + ll[7][row]));
        float v = (accl[0][row * 66 + col] + accl[1][row * 66 + col]) +
                  (accl[2][row * 66 + col] + accl[3][row * 66 + col]);
        v /= lsum;
        v = (v > 0.f) ? v : expm1f(v);
        ob[(size_t)row * OUTD + col] = v;
    }
}

// ---------------------------------------------------------------------------
extern "C" void kernel_launch(void* const* d_in, const int* in_sizes, int n_in,
                              void* d_out, int out_size, void* d_ws, size_t ws_size,
                              hipStream_t stream)
{
    const float* h     = (const float*)d_in[0];
    const float* W     = (const float*)d_in[1];
    const float* bfc   = (const float*)d_in[2];
    const float* asrc  = (const float*)d_in[3];
    const float* adst  = (const float*)d_in[4];
    const float* battn = (const float*)d_in[5];
    float* out = (float*)d_out;

    unsigned short* hpT2 = (unsigned short*)d_ws;            // 2 MB f16 tiled
    float*     s = (float*)((char*)d_ws + (size_t)BB * NN * OUTD * 2);
    _Float16*  F = (_Float16*)(s + (size_t)BB * NN);
    _Float16*  H = F + (size_t)BB * NN;

    gat_proj_kernel<<<(BB * NN) / 64, 512, 0, stream>>>(h, W, bfc, asrc, adst,
                                                        hpT2, s, F, H);
    gat_attn_kernel<<<BB * (NN / 64), 512, 0, stream>>>(hpT2, s, F, H, battn, out);
}